// Round 1
// baseline (39.452 us; speedup 1.0000x reference)
//
#include <hip/hip_runtime.h>

// TT-embedding: voc_quant (32,32,32), emb_quant (8,8,16), ranks (1,8,8,1).
// out[n, e0*128+e1*16+e2] = sum_{r1,r2} c0[i0][e0][r1]*c1[i1][r1][e1][r2]*c2[i2][r2][e2]
// Write-BW-bound: 128 MB fp32 output, ~0.8 GFLOP compute.

__global__ __launch_bounds__(256) void tt_emb_kernel(
    const int* __restrict__ x,
    const float* __restrict__ c0,   // [32][1][8][8]  = 64 floats/row
    const float* __restrict__ c1,   // [32][8][8][8]  = 512 floats/row
    const float* __restrict__ c2,   // [32][8][16][1] = 128 floats/row
    float* __restrict__ out)        // [N][1024]
{
    const int n = blockIdx.x;
    const int t = threadIdx.x;

    __shared__ float s0[64];
    __shared__ float s1[512];
    __shared__ float s2[128];

    const int flat = x[n];              // broadcast load, all lanes same addr
    const int i0 = (flat >> 10) & 31;
    const int i1 = (flat >> 5) & 31;
    const int i2 = flat & 31;

    // cooperative staging of the three selected core rows (704 floats, 2.8 KB)
    if (t < 64)  s0[t] = c0[i0 * 64 + t];
    s1[t]        = c1[i1 * 512 + t];
    s1[t + 256]  = c1[i1 * 512 + 256 + t];
    if (t < 128) s2[t] = c2[i2 * 128 + t];
    __syncthreads();

    // thread t owns (e0,e1) = (t>>5, (t>>2)&7) and e2 in [ (t&3)*4, +4 )
    const int e0  = t >> 5;
    const int e1  = (t >> 2) & 7;
    const int e2b = (t & 3) << 2;

    // tmp[r2] = sum_r1 g0[e0][r1] * g1[r1][e1][r2]
    float tmp[8] = {0.f, 0.f, 0.f, 0.f, 0.f, 0.f, 0.f, 0.f};
    #pragma unroll
    for (int r1 = 0; r1 < 8; ++r1) {
        const float a = s0[e0 * 8 + r1];
        #pragma unroll
        for (int r2 = 0; r2 < 8; ++r2)
            tmp[r2] = fmaf(a, s1[r1 * 64 + e1 * 8 + r2], tmp[r2]);
    }

    // res[q] = sum_r2 tmp[r2] * g2[r2][e2b+q]
    float res[4];
    #pragma unroll
    for (int q = 0; q < 4; ++q) {
        float acc = 0.f;
        #pragma unroll
        for (int r2 = 0; r2 < 8; ++r2)
            acc = fmaf(tmp[r2], s2[r2 * 16 + e2b + q], acc);
        res[q] = acc;
    }

    // padding_idx == 0 -> zero row
    if (flat == 0) { res[0] = res[1] = res[2] = res[3] = 0.f; }

    float4 o = make_float4(res[0], res[1], res[2], res[3]);
    *reinterpret_cast<float4*>(out + (size_t)n * 1024 + (size_t)t * 4) = o;
}

extern "C" void kernel_launch(void* const* d_in, const int* in_sizes, int n_in,
                              void* d_out, int out_size, void* d_ws, size_t ws_size,
                              hipStream_t stream) {
    const int*   x  = (const int*)d_in[0];     // 32768 indices (int64 -> int32 by harness)
    const float* c0 = (const float*)d_in[1];   // 2048
    const float* c1 = (const float*)d_in[2];   // 16384
    const float* c2 = (const float*)d_in[3];   // 4096
    float* out = (float*)d_out;                // 33554432 fp32

    const int N = in_sizes[0];                 // 32768
    tt_emb_kernel<<<N, 256, 0, stream>>>(x, c0, c1, c2, out);
}